// Round 1
// baseline (2348.429 us; speedup 1.0000x reference)
//
#include <hip/hip_runtime.h>

#define NNODES 100000
#define NEDGES 1600000
#define NODE_IN 128
#define EDGE_IN 64
#define OUT_DIM 128

// ---------------------------------------------------------------------------
// Phase 1: edge scatter. One wave (64 lanes) per edge.
//   A[dst] += node_feats[src]   (128 f32, 2 per lane)
//   B[dst] += edge_feats[e]     (64 f32, 1 per lane)
//   deg[dst] += 1               (lane 0)
// ---------------------------------------------------------------------------
__global__ __launch_bounds__(256) void edge_scatter_kernel(
    const float* __restrict__ node_feats, const float* __restrict__ edge_feats,
    const int* __restrict__ src, const int* __restrict__ dst,
    float* __restrict__ A, float* __restrict__ B, int* __restrict__ deg)
{
    const int lane   = threadIdx.x & 63;
    const int wave   = (blockIdx.x * blockDim.x + threadIdx.x) >> 6;
    const int nwaves = (gridDim.x * blockDim.x) >> 6;

    for (int e = wave; e < NEDGES; e += nwaves) {
        const int s = src[e];   // same addr across wave -> broadcast
        const int d = dst[e];

        const float2 nf = *reinterpret_cast<const float2*>(
            node_feats + (size_t)s * NODE_IN + lane * 2);
        const float  ef = edge_feats[(size_t)e * EDGE_IN + lane];

        float* Ad = A + (size_t)d * NODE_IN + lane * 2;
        atomicAdd(Ad,     nf.x);
        atomicAdd(Ad + 1, nf.y);
        atomicAdd(B + (size_t)d * EDGE_IN + lane, ef);
        if (lane == 0) atomicAdd(deg + d, 1);
    }
}

// ---------------------------------------------------------------------------
// Phase 2: node GEMM.  out[v] = A[v] @ Wn + B[v] @ We + deg[v]*(bn+be)
// Treated as [NNODES,192] @ [192,128]. Weights staged once per block in LDS
// (96 KB). 512 threads = 8 waves; each wave register-blocks 4 rows, each lane
// owns output cols {lane, lane+64}. LDS reads amortized 4x by row blocking.
// ---------------------------------------------------------------------------
__global__ __launch_bounds__(512) void node_gemm_kernel(
    const float* __restrict__ A, const float* __restrict__ B,
    const int* __restrict__ deg,
    const float* __restrict__ Wn, const float* __restrict__ bn,
    const float* __restrict__ We, const float* __restrict__ be,
    float* __restrict__ out)
{
    __shared__ float Wsh[192 * 128];   // rows 0..127 = Wn, rows 128..191 = We
    __shared__ float bb[128];

    for (int i = threadIdx.x; i < NODE_IN * OUT_DIM; i += 512) Wsh[i] = Wn[i];
    for (int i = threadIdx.x; i < EDGE_IN * OUT_DIM; i += 512)
        Wsh[NODE_IN * OUT_DIM + i] = We[i];
    if (threadIdx.x < 128) bb[threadIdx.x] = bn[threadIdx.x] + be[threadIdx.x];
    __syncthreads();

    const int lane    = threadIdx.x & 63;
    const int wid     = threadIdx.x >> 6;                 // 0..7
    const int rowBase = blockIdx.x * 32 + wid * 4;        // 4 rows per wave
    if (rowBase >= NNODES) return;                        // exact fit: 3125*32

    float acc[4][2];
#pragma unroll
    for (int r = 0; r < 4; r++) {
        const float dg = (float)deg[rowBase + r];
        acc[r][0] = dg * bb[lane];
        acc[r][1] = dg * bb[lane + 64];
    }

    // --- A @ Wn : k = 0..127 ---
    const float* Ap = A + (size_t)rowBase * NODE_IN;
    for (int k0 = 0; k0 < NODE_IN; k0 += 4) {
        float4 a[4];
#pragma unroll
        for (int r = 0; r < 4; r++)
            a[r] = *reinterpret_cast<const float4*>(Ap + r * NODE_IN + k0);
#pragma unroll
        for (int j = 0; j < 4; j++) {
            const float w0 = Wsh[(k0 + j) * 128 + lane];
            const float w1 = Wsh[(k0 + j) * 128 + lane + 64];
#pragma unroll
            for (int r = 0; r < 4; r++) {
                const float av = (j == 0) ? a[r].x : (j == 1) ? a[r].y
                               : (j == 2) ? a[r].z : a[r].w;
                acc[r][0] = fmaf(av, w0, acc[r][0]);
                acc[r][1] = fmaf(av, w1, acc[r][1]);
            }
        }
    }

    // --- B @ We : k = 0..63 (rows 128..191 of Wsh) ---
    const float* Bp = B + (size_t)rowBase * EDGE_IN;
    for (int k0 = 0; k0 < EDGE_IN; k0 += 4) {
        float4 b[4];
#pragma unroll
        for (int r = 0; r < 4; r++)
            b[r] = *reinterpret_cast<const float4*>(Bp + r * EDGE_IN + k0);
#pragma unroll
        for (int j = 0; j < 4; j++) {
            const float w0 = Wsh[(128 + k0 + j) * 128 + lane];
            const float w1 = Wsh[(128 + k0 + j) * 128 + lane + 64];
#pragma unroll
            for (int r = 0; r < 4; r++) {
                const float bv = (j == 0) ? b[r].x : (j == 1) ? b[r].y
                               : (j == 2) ? b[r].z : b[r].w;
                acc[r][0] = fmaf(bv, w0, acc[r][0]);
                acc[r][1] = fmaf(bv, w1, acc[r][1]);
            }
        }
    }

#pragma unroll
    for (int r = 0; r < 4; r++) {
        out[(size_t)(rowBase + r) * OUT_DIM + lane]      = acc[r][0];
        out[(size_t)(rowBase + r) * OUT_DIM + lane + 64] = acc[r][1];
    }
}

extern "C" void kernel_launch(void* const* d_in, const int* in_sizes, int n_in,
                              void* d_out, int out_size, void* d_ws, size_t ws_size,
                              hipStream_t stream) {
    const float* node_feats = (const float*)d_in[0];
    const float* edge_feats = (const float*)d_in[1];
    const int*   src        = (const int*)d_in[2];
    const int*   dst        = (const int*)d_in[3];
    const float* Wn         = (const float*)d_in[4];
    const float* bn         = (const float*)d_in[5];
    const float* We         = (const float*)d_in[6];
    const float* be         = (const float*)d_in[7];
    float* out = (float*)d_out;

    // Workspace layout: A [NNODES,128] f32 | B [NNODES,64] f32 | deg [NNODES] i32
    float* A   = (float*)d_ws;
    float* B   = A + (size_t)NNODES * NODE_IN;
    int*   deg = (int*)(B + (size_t)NNODES * EDGE_IN);
    const size_t zero_bytes =
        ((size_t)NNODES * NODE_IN + (size_t)NNODES * EDGE_IN + NNODES) * 4;

    hipMemsetAsync(d_ws, 0, zero_bytes, stream);

    // 2048 blocks * 256 thr = 8192 waves, 8 blocks/CU -> full occupancy,
    // grid-stride over 1.6M edges.
    edge_scatter_kernel<<<2048, 256, 0, stream>>>(
        node_feats, edge_feats, src, dst, A, B, deg);

    // 3125 blocks * 32 rows = 100000 rows exactly.
    node_gemm_kernel<<<3125, 512, 0, stream>>>(
        A, B, deg, Wn, bn, We, be, out);
}

// Round 4
// 1202.218 us; speedup vs baseline: 1.9534x; 1.9534x over previous
//
#include <hip/hip_runtime.h>

#define NNODES 100000
#define NEDGES 1600000
#define NODE_IN 128
#define EDGE_IN 64
#define OUT_DIM 128

// ---------------------------------------------------------------------------
// K1: histogram of dst. cnt[] is 400 KB -> L2-resident int atomics (cheap).
// ---------------------------------------------------------------------------
__global__ __launch_bounds__(256) void hist_kernel(const int* __restrict__ dst,
                                                   int* __restrict__ cnt)
{
    int i = blockIdx.x * blockDim.x + threadIdx.x;
    const int stride = gridDim.x * blockDim.x;
    for (; i < NEDGES; i += stride) atomicAdd(cnt + dst[i], 1);
}

// ---------------------------------------------------------------------------
// K2: single-block exclusive prefix scan of cnt -> cursor (exclusive starts).
// After K3's atomic increments, cursor[n] becomes the segment END for node n,
// so (cursor[n-1], cursor[n]) bounds node n's edge list -- no separate start[].
// ---------------------------------------------------------------------------
__global__ __launch_bounds__(1024) void scan_kernel(const int* __restrict__ cnt,
                                                    int* __restrict__ cursor)
{
    __shared__ int wsum[16];
    __shared__ int wpre[16];
    __shared__ int carry_s;
    __shared__ int btot;

    const int tid = threadIdx.x, lane = tid & 63, wid = tid >> 6;
    if (tid == 0) carry_s = 0;
    __syncthreads();

    for (int base = 0; base < NNODES; base += 1024) {
        const int i = base + tid;
        const int v = (i < NNODES) ? cnt[i] : 0;

        int s = v;
#pragma unroll
        for (int d = 1; d < 64; d <<= 1) {
            int t = __shfl_up(s, d, 64);
            if (lane >= d) s += t;
        }
        if (lane == 63) wsum[wid] = s;
        __syncthreads();

        if (wid == 0) {
            int w  = (lane < 16) ? wsum[lane] : 0;
            int ws = w;
#pragma unroll
            for (int d = 1; d < 16; d <<= 1) {
                int t = __shfl_up(ws, d, 64);
                if (lane >= d) ws += t;
            }
            if (lane < 16)  wpre[lane] = ws - w;
            if (lane == 15) btot = ws;
        }
        __syncthreads();

        const int excl = s - v + wpre[wid] + carry_s;
        if (i < NNODES) cursor[i] = excl;
        __syncthreads();
        if (tid == 0) carry_s += btot;
        __syncthreads();
    }
}

// ---------------------------------------------------------------------------
// K3: scatter (edge_id, src_id) pairs into dst-sorted order. 1.6M int atomics
// on L2-resident cursor; 8B writes random into 12.8 MB (cache-absorbed).
// Storing src alongside the edge id removes a dependent load from K4's
// per-edge critical path.
// ---------------------------------------------------------------------------
__global__ __launch_bounds__(256) void scatter_kernel(const int* __restrict__ dst,
                                                      const int* __restrict__ src,
                                                      int* __restrict__ cursor,
                                                      int2* __restrict__ perm2)
{
    int i = blockIdx.x * blockDim.x + threadIdx.x;
    const int stride = gridDim.x * blockDim.x;
    for (; i < NEDGES; i += stride) {
        const int d   = dst[i];
        const int pos = atomicAdd(cursor + d, 1);
        perm2[pos] = make_int2(i, src[i]);
    }
}

// ---------------------------------------------------------------------------
// K4: atomic-free accumulation. One wave per node: sum node_feats[src] (2 f32
// per lane) and edge_feats[e] (1 f32 per lane) over the node's edge list.
// A rows are staged in d_out (exactly [NNODES,128] f32) to cut ws usage;
// K5 reads its own rows then overwrites them (same-wave program order: safe).
// ---------------------------------------------------------------------------
__global__ __launch_bounds__(256) void accumulate_kernel(
    const float* __restrict__ node_feats, const float* __restrict__ edge_feats,
    const int2* __restrict__ perm2, const int* __restrict__ cursor,
    float* __restrict__ A, float* __restrict__ B)
{
    const int lane = threadIdx.x & 63;
    const int n    = (blockIdx.x * blockDim.x + threadIdx.x) >> 6;
    if (n >= NNODES) return;

    const int st = (n == 0) ? 0 : cursor[n - 1];
    const int en = cursor[n];

    float a0 = 0.f, a1 = 0.f, b0 = 0.f;

    // 1-deep prefetch of (edge id, src id) to hide the broadcast-load latency.
    int2 p_cur = make_int2(0, 0);
    if (st < en) p_cur = perm2[st];

    for (int i = st; i < en; ++i) {
        const int e = p_cur.x;
        const int s = p_cur.y;
        if (i + 1 < en) p_cur = perm2[i + 1];

        const float2 nf = *reinterpret_cast<const float2*>(
            node_feats + (size_t)s * NODE_IN + lane * 2);
        const float ef = edge_feats[(size_t)e * EDGE_IN + lane];
        a0 += nf.x; a1 += nf.y; b0 += ef;
    }

    *reinterpret_cast<float2*>(A + (size_t)n * NODE_IN + lane * 2) =
        make_float2(a0, a1);
    B[(size_t)n * EDGE_IN + lane] = b0;
}

// ---------------------------------------------------------------------------
// K5: node GEMM. out[v] = A[v]@Wn + B[v]@We + deg[v]*(bn+be).
// A lives in d_out; each wave reads only its own 8 rows, then overwrites
// those same 8 rows (reads complete before writes in program order -> safe).
// 1024 threads (16 waves) + 96KB LDS -> 1 block/CU, 4 waves/SIMD.
// ---------------------------------------------------------------------------
__global__ __launch_bounds__(1024) void node_gemm_kernel(
    const float* __restrict__ B, const int* __restrict__ deg,
    const float* __restrict__ Wn, const float* __restrict__ bn,
    const float* __restrict__ We, const float* __restrict__ be,
    float* out)   // A-in and out-out alias: no __restrict__
{
    __shared__ float Wsh[192 * 128];   // rows 0..127 = Wn, 128..191 = We
    __shared__ float bb[128];

    for (int i = threadIdx.x; i < NODE_IN * OUT_DIM; i += 1024) Wsh[i] = Wn[i];
    for (int i = threadIdx.x; i < EDGE_IN * OUT_DIM; i += 1024)
        Wsh[NODE_IN * OUT_DIM + i] = We[i];
    if (threadIdx.x < 128) bb[threadIdx.x] = bn[threadIdx.x] + be[threadIdx.x];
    __syncthreads();

    const int lane    = threadIdx.x & 63;
    const int wid     = threadIdx.x >> 6;                 // 0..15
    const int rowBase = blockIdx.x * 128 + wid * 8;       // 8 rows per wave
    if (rowBase >= NNODES) return;                        // 100000 % 8 == 0

    float acc[8][2];
#pragma unroll
    for (int r = 0; r < 8; r++) {
        const float dg = (float)deg[rowBase + r];
        acc[r][0] = dg * bb[lane];
        acc[r][1] = dg * bb[lane + 64];
    }

    // --- A @ Wn : k = 0..127 (A rows read from `out`) ---
    const float* Ap = out + (size_t)rowBase * NODE_IN;
    for (int k0 = 0; k0 < NODE_IN; k0 += 4) {
        float4 a[8];
#pragma unroll
        for (int r = 0; r < 8; r++)
            a[r] = *reinterpret_cast<const float4*>(Ap + r * NODE_IN + k0);
#pragma unroll
        for (int j = 0; j < 4; j++) {
            const float w0 = Wsh[(k0 + j) * 128 + lane];
            const float w1 = Wsh[(k0 + j) * 128 + lane + 64];
#pragma unroll
            for (int r = 0; r < 8; r++) {
                const float av = (j == 0) ? a[r].x : (j == 1) ? a[r].y
                               : (j == 2) ? a[r].z : a[r].w;
                acc[r][0] = fmaf(av, w0, acc[r][0]);
                acc[r][1] = fmaf(av, w1, acc[r][1]);
            }
        }
    }

    // --- B @ We : k = 0..63 (rows 128..191 of Wsh) ---
    const float* Bp = B + (size_t)rowBase * EDGE_IN;
    for (int k0 = 0; k0 < EDGE_IN; k0 += 4) {
        float4 b[8];
#pragma unroll
        for (int r = 0; r < 8; r++)
            b[r] = *reinterpret_cast<const float4*>(Bp + r * EDGE_IN + k0);
#pragma unroll
        for (int j = 0; j < 4; j++) {
            const float w0 = Wsh[(128 + k0 + j) * 128 + lane];
            const float w1 = Wsh[(128 + k0 + j) * 128 + lane + 64];
#pragma unroll
            for (int r = 0; r < 8; r++) {
                const float bv = (j == 0) ? b[r].x : (j == 1) ? b[r].y
                               : (j == 2) ? b[r].z : b[r].w;
                acc[r][0] = fmaf(bv, w0, acc[r][0]);
                acc[r][1] = fmaf(bv, w1, acc[r][1]);
            }
        }
    }

#pragma unroll
    for (int r = 0; r < 8; r++) {
        out[(size_t)(rowBase + r) * OUT_DIM + lane]      = acc[r][0];
        out[(size_t)(rowBase + r) * OUT_DIM + lane + 64] = acc[r][1];
    }
}

extern "C" void kernel_launch(void* const* d_in, const int* in_sizes, int n_in,
                              void* d_out, int out_size, void* d_ws, size_t ws_size,
                              hipStream_t stream) {
    const float* node_feats = (const float*)d_in[0];
    const float* edge_feats = (const float*)d_in[1];
    const int*   src        = (const int*)d_in[2];
    const int*   dst        = (const int*)d_in[3];
    const float* Wn         = (const float*)d_in[4];
    const float* bn         = (const float*)d_in[5];
    const float* We         = (const float*)d_in[6];
    const float* be         = (const float*)d_in[7];
    float* out = (float*)d_out;

    // Workspace layout (39.2 MB total; A is staged in d_out itself):
    //   perm2  [NEDGES]     int2  12.8 MB  (8B-aligned at ws base)
    //   B      [NNODES, 64] f32   25.6 MB
    //   cnt    [NNODES]     i32    0.4 MB  (doubles as deg)
    //   cursor [NNODES]     i32    0.4 MB
    int2*  perm2  = (int2*)d_ws;
    float* B      = (float*)(perm2 + NEDGES);
    int*   cnt    = (int*)(B + (size_t)NNODES * EDGE_IN);
    int*   cursor = cnt + NNODES;
    float* A      = out;   // [NNODES,128] staging, overwritten in-place by K5

    // Only cnt must be zeroed; everything else is written before read.
    hipMemsetAsync(cnt, 0, (size_t)NNODES * sizeof(int), stream);

    hist_kernel<<<2048, 256, 0, stream>>>(dst, cnt);
    scan_kernel<<<1, 1024, 0, stream>>>(cnt, cursor);
    scatter_kernel<<<2048, 256, 0, stream>>>(dst, src, cursor, perm2);

    // 100000 waves, 4 waves per 256-thread block.
    accumulate_kernel<<<25000, 256, 0, stream>>>(
        node_feats, edge_feats, perm2, cursor, A, B);

    // 782 blocks * 128 rows >= 100000.
    node_gemm_kernel<<<782, 1024, 0, stream>>>(
        B, cnt, Wn, bn, We, be, out);
}